// Round 11
// baseline (311.586 us; speedup 1.0000x reference)
//
#include <hip/hip_runtime.h>
#include <hip/hip_bf16.h>
#include <stdint.h>

#define M_DIM 8192   // 4*2048
#define N_DIM 4096   // OUT_FEATURES
#define K_DIM 4096   // IN_FEATURES
#define KB2   (K_DIM * 2)   // bytes per K-row

typedef __attribute__((ext_vector_type(8))) __bf16 bf16x8;
typedef __attribute__((ext_vector_type(4))) float  f32x4;

#define GLD_LDS16(gaddr, laddr)                                            \
  __builtin_amdgcn_global_load_lds(                                        \
      (const __attribute__((address_space(1))) uint32_t*)(gaddr),          \
      (__attribute__((address_space(3))) uint32_t*)(laddr), 16, 0, 0)

// ---------------------------------------------------------------------------
// Merged prep: blocks [0,2048) dequant qweight->Wb bf16; [2048,18432) cvt x->bf16
// ---------------------------------------------------------------------------
__global__ __launch_bounds__(256) void prep_kernel(
    const int* __restrict__ q, const float* __restrict__ lut,
    __bf16* __restrict__ Wb,
    const float* __restrict__ x, __bf16* __restrict__ xb) {
  int b = blockIdx.x;
  if (b < 2048) {
    int t = b * 256 + threadIdx.x;   // 0 .. O*128-1
    int o = t >> 7;
    int w = t & 127;
    const int PLANE = N_DIM * (K_DIM / 32);
    int base = o * (K_DIM / 32) + w;
    uint32_t q0 = (uint32_t)q[0 * PLANE + base];
    uint32_t q1 = (uint32_t)q[1 * PLANE + base];
    uint32_t q2 = (uint32_t)q[2 * PLANE + base];
    uint32_t q3 = (uint32_t)q[3 * PLANE + base];
    const float* lrow = lut + o * 16;
    __bf16 vals[32];
#pragma unroll
    for (int i = 0; i < 32; ++i) {
      uint32_t idx = ((q0 >> i) & 1u) | (((q1 >> i) & 1u) << 1) |
                     (((q2 >> i) & 1u) << 2) | (((q3 >> i) & 1u) << 3);
      vals[i] = (__bf16)lrow[idx];
    }
    bf16x8* dst = (bf16x8*)(Wb + (size_t)o * K_DIM + w * 32);
#pragma unroll
    for (int r = 0; r < 4; ++r) {
      bf16x8 v;
#pragma unroll
      for (int j = 0; j < 8; ++j) v[j] = vals[r * 8 + j];
      dst[r] = v;
    }
  } else {
    int t = (b - 2048) * 256 + threadIdx.x;   // 0 .. 4194303 (exact)
    f32x4 a = ((const f32x4*)x)[t * 2];
    f32x4 c = ((const f32x4*)x)[t * 2 + 1];
    bf16x8 v;
    v[0] = (__bf16)a[0]; v[1] = (__bf16)a[1]; v[2] = (__bf16)a[2]; v[3] = (__bf16)a[3];
    v[4] = (__bf16)c[0]; v[5] = (__bf16)c[1]; v[6] = (__bf16)c[2]; v[7] = (__bf16)c[3];
    ((bf16x8*)xb)[t] = v;
  }
}

// ---------------------------------------------------------------------------
// 256x256 bf16 GEMM, R11 = R8 schedule (frozen) + SUBTILE-MAJOR LINEAR LDS.
// LDS: [buf][mat][half][16 subtiles x 1KB]. Subtile (f,ks) at (f*2+ks)*1024;
// lane l's 16B at +l*16 holds X[f*16 + (l&15)][ks*32 + (l>>4)*8 .. +8]
// == exactly the mfma_16x16x32 fragment slot. Staged via global_load_lds
// (wave-uniform dest = subtile base, per-lane permuted SOURCE address).
// Every ds_read_b128 is base + l*16 (ideal linear). Sync = R8: collective
// certs vmcnt(4) end-p3/p7 before barrier; lgkm-relaxed MFMA clusters.
// ---------------------------------------------------------------------------
__global__ __launch_bounds__(512, 2) void anyprec_gemm_kernel(
    const __bf16* __restrict__ A,   // M x K bf16
    const __bf16* __restrict__ B,   // N x K bf16
    const float* __restrict__ bias,
    float* __restrict__ C) {
  __shared__ __bf16 lds[2][2][2][8192];   // 131072 B

  // XCD-aware bijective swizzle (512 wgs, 512%8==0)
  int bid = blockIdx.x;
  int swz = (bid & 7) * 64 + (bid >> 3);
  int mb = swz >> 4;    // 32 m-tiles
  int nb = swz & 15;    // 16 n-tiles

  const int tid  = threadIdx.x;
  const int lane = tid & 63;
  const int wid  = tid >> 6;
  const int wr   = wid >> 2;   // 0..1
  const int wc   = wid & 3;    // 0..3

  // staging: wave wid stages subtiles (f=wid, ks=0/1) of each half-tile.
  // per-lane source components: row-in-16 = lane&15, k-in-32 = (lane>>4)*8
  const int rA = lane & 15;
  const int kA = (lane >> 4) << 3;
  const char* gAs = (const char*)A + (size_t)(mb * 256 + wid * 16 + rA) * KB2 + kA * 2;
  const char* gBs = (const char*)B + (size_t)(nb * 256 + wid * 16 + rA) * KB2 + kA * 2;

  f32x4 acc[2][2][4][2];
#pragma unroll
  for (int qm = 0; qm < 2; ++qm)
#pragma unroll
    for (int qn = 0; qn < 2; ++qn)
#pragma unroll
      for (int mf = 0; mf < 4; ++mf)
#pragma unroll
        for (int nf = 0; nf < 2; ++nf) acc[qm][qn][mf][nf] = (f32x4)0.0f;

  bf16x8 a0[4][2], a1[4][2], b0[2][2], b1[2][2];

// stage half-tile (mat,h) of K-tile t into lds[buf][mat][h]:
// 2 gld_lds per wave (ks=0,1), dest lane-invariant, source per-lane.
#define STAGE(mat, h, buf, t) {                                            \
    char* lb_ = (char*)&lds[buf][mat][h][0] + wid * 2048;                  \
    const char* gb_ = (mat ? gBs : gAs) + (size_t)(h) * 128 * KB2          \
                      + (size_t)(t) * 128;                                 \
    GLD_LDS16(gb_,      lb_);                                              \
    GLD_LDS16(gb_ + 64, lb_ + 1024); }

#define LDA(dst, qm, buf) {                                                \
    const char* p_ = (const char*)&lds[buf][0][qm][0] + wr * 8192          \
                     + lane * 16;                                          \
    _Pragma("unroll")                                                      \
    for (int mf = 0; mf < 4; ++mf) {                                       \
      dst[mf][0] = *(const bf16x8*)(p_ + mf * 2048);                       \
      dst[mf][1] = *(const bf16x8*)(p_ + mf * 2048 + 1024); } }

#define LDB(dst, qn, buf) {                                                \
    const char* p_ = (const char*)&lds[buf][1][qn][0] + wc * 4096          \
                     + lane * 16;                                          \
    _Pragma("unroll")                                                      \
    for (int nf = 0; nf < 2; ++nf) {                                       \
      dst[nf][0] = *(const bf16x8*)(p_ + nf * 2048);                       \
      dst[nf][1] = *(const bf16x8*)(p_ + nf * 2048 + 1024); } }

#define MMA(qm, qn, aa, bb) {                                              \
    _Pragma("unroll")                                                      \
    for (int mf = 0; mf < 4; ++mf)                                         \
      _Pragma("unroll")                                                    \
      for (int nf = 0; nf < 2; ++nf) {                                     \
        acc[qm][qn][mf][nf] = __builtin_amdgcn_mfma_f32_16x16x32_bf16(     \
            aa[mf][0], bb[nf][0], acc[qm][qn][mf][nf], 0, 0, 0);           \
        acc[qm][qn][mf][nf] = __builtin_amdgcn_mfma_f32_16x16x32_bf16(     \
            aa[mf][1], bb[nf][1], acc[qm][qn][mf][nf], 0, 0, 0); } }

#define PRIO1 __builtin_amdgcn_s_setprio(1);
#define PRIO0 __builtin_amdgcn_s_setprio(0);
#define BAR   __builtin_amdgcn_s_barrier();
#define VMC(n) asm volatile("s_waitcnt vmcnt(" #n ")" ::: "memory");

  // ---- prologue: stage tile0 + A0,B1,A1 of tile1; collective-cert tile0
  STAGE(0, 0, 0, 0);  // A0(0)
  STAGE(1, 0, 0, 0);  // B0(0)
  STAGE(1, 1, 0, 0);  // B1(0)
  STAGE(0, 1, 0, 0);  // A1(0)
  STAGE(0, 0, 1, 1);  // A0(1)
  STAGE(1, 1, 1, 1);  // B1(1)
  STAGE(0, 1, 1, 1);  // A1(1)
  VMC(6); BAR;        // tile0 certified for ALL waves
  LDA(a0, 0, 0); LDB(b0, 0, 0);   // consumed in p1

  // ---- main loop: tiles E=2i (buf0), O=2i+1 (buf1), i = 0..30
  for (int i = 0; i < 31; ++i) {
    const int t1 = 2 * i + 1, t2 = 2 * i + 2, t3 = 2 * i + 3;
    // p1: MMA(0,0)E ; load B1(E) ; stage B0(O)
    STAGE(1, 0, 1, t1);
    PRIO1; LDB(b1, 1, 0); MMA(0, 0, a0, b0); PRIO0; BAR;
    // p2: MMA(0,1)E ; load A1(E) ; stage A0(E+2)
    STAGE(0, 0, 0, t2);
    PRIO1; LDA(a1, 1, 0); MMA(0, 1, a0, b1); PRIO0; BAR;
    // p3: MMA(1,1)E ; stage B1(E+2) ; COLLECTIVE cert of tile O at end
    STAGE(1, 1, 0, t2);
    PRIO1; MMA(1, 1, a1, b1); PRIO0; VMC(4); BAR;
    // p4: MMA(1,0)E ; load A0(O), B0(O) (certified) ; stage A1(E+2)
    STAGE(0, 1, 0, t2);
    PRIO1; LDA(a0, 0, 1); MMA(1, 0, a1, b0); LDB(b0, 0, 1); PRIO0; BAR;
    // p5: MMA(0,0)O ; load B1(O) ; stage B0(E+2)
    STAGE(1, 0, 0, t2);
    PRIO1; LDB(b1, 1, 1); MMA(0, 0, a0, b0); PRIO0; BAR;
    // p6: MMA(0,1)O ; load A1(O) ; stage A0(O+2)
    STAGE(0, 0, 1, t3);
    PRIO1; LDA(a1, 1, 1); MMA(0, 1, a0, b1); PRIO0; BAR;
    // p7: MMA(1,1)O ; stage B1(O+2) ; COLLECTIVE cert of tile E+2 at end
    STAGE(1, 1, 1, t3);
    PRIO1; MMA(1, 1, a1, b1); PRIO0; VMC(4); BAR;
    // p8: MMA(1,0)O ; load A0(E+2), B0(E+2) (certified) ; stage A1(O+2)
    STAGE(0, 1, 1, t3);
    PRIO1; LDA(a0, 0, 0); MMA(1, 0, a1, b0); LDB(b0, 0, 0); PRIO0; BAR;
  }

  // ---- tail: tiles 62 (buf0), 63 (buf1); regs hold a0,b0 of 62;
  //      outstanding stages: A0(63),B1(63),A1(63)
  STAGE(1, 0, 1, 63);                         // B0(63)
  PRIO1; LDB(b1, 1, 0); MMA(0, 0, a0, b0); PRIO0; BAR;
  PRIO1; LDA(a1, 1, 0); MMA(0, 1, a0, b1); PRIO0; BAR;
  PRIO1; MMA(1, 1, a1, b1); PRIO0; VMC(0); BAR;   // tile 63 collective-certified
  PRIO1; LDA(a0, 0, 1); MMA(1, 0, a1, b0); LDB(b0, 0, 1); PRIO0; BAR;
  PRIO1; LDB(b1, 1, 1); MMA(0, 0, a0, b0); PRIO0; BAR;
  PRIO1; LDA(a1, 1, 1); MMA(0, 1, a0, b1); PRIO0; BAR;
  MMA(1, 1, a1, b1);
  MMA(1, 0, a1, b0);

  // ---- epilogue: C/D layout col=lane&15, row=(lane>>4)*4+j
  const int cL = lane & 15;
  const int rL = (lane >> 4) * 4;
#pragma unroll
  for (int qn = 0; qn < 2; ++qn)
#pragma unroll
    for (int nf = 0; nf < 2; ++nf) {
      int col = nb * 256 + qn * 128 + wc * 32 + nf * 16 + cL;
      float bv = bias[col];
#pragma unroll
      for (int qm = 0; qm < 2; ++qm)
#pragma unroll
        for (int mf = 0; mf < 4; ++mf) {
          int row0 = mb * 256 + qm * 128 + wr * 64 + mf * 16 + rL;
#pragma unroll
          for (int j = 0; j < 4; ++j)
            C[(size_t)(row0 + j) * N_DIM + col] = acc[qm][qn][mf][nf][j] + bv;
        }
    }
#undef STAGE
#undef LDA
#undef LDB
#undef MMA
#undef PRIO1
#undef PRIO0
#undef BAR
#undef VMC
}

extern "C" void kernel_launch(void* const* d_in, const int* in_sizes, int n_in,
                              void* d_out, int out_size, void* d_ws, size_t ws_size,
                              hipStream_t stream) {
  const float* x    = (const float*)d_in[0];
  const int*   qw   = (const int*)d_in[1];
  const float* lut  = (const float*)d_in[2];
  const float* bias = (const float*)d_in[3];

  __bf16* Wb = (__bf16*)d_ws;
  __bf16* Xb = (__bf16*)((char*)d_ws + (size_t)N_DIM * K_DIM * 2);

  {
    // 2048 dequant blocks + 16384 cvt blocks in one launch
    prep_kernel<<<18432, 256, 0, stream>>>(qw, lut, Wb, x, Xb);
  }
  {
    dim3 grid((M_DIM / 256) * (N_DIM / 256));  // 32*16 = 512
    anyprec_gemm_kernel<<<grid, 512, 0, stream>>>(Xb, Wb, bias, (float*)d_out);
  }
}

// Round 12
// 273.729 us; speedup vs baseline: 1.1383x; 1.1383x over previous
//
#include <hip/hip_runtime.h>
#include <hip/hip_bf16.h>
#include <stdint.h>

#define M_DIM 8192   // 4*2048
#define N_DIM 4096   // OUT_FEATURES
#define K_DIM 4096   // IN_FEATURES

typedef __attribute__((ext_vector_type(8)))  __bf16 bf16x8;
typedef __attribute__((ext_vector_type(4)))  float  f32x4;
typedef __attribute__((ext_vector_type(16))) float  f32x16;

#define GLD_LDS16(gaddr, laddr)                                            \
  __builtin_amdgcn_global_load_lds(                                        \
      (const __attribute__((address_space(1))) uint32_t*)(gaddr),          \
      (__attribute__((address_space(3))) uint32_t*)(laddr), 16, 0, 0)

// ---------------------------------------------------------------------------
// Subtile-major layout (both Xf and Wf), designed for mfma_32x32x16 fragments:
//  row-panel rt = row>>8 (256 rows); K-tile t = k>>6 (64 k); half h=(row>>7)&1;
//  row-group rg=(row>>5)&3; k-seg ks=(k>>4)&3; lane slot l=(row&31)+32*((k>>3)&1)
//  byte = ((rt*64+t)*32768) + h*16384 + (rg*4+ks)*1024 + l*16
// Half-tile (16 KB) is contiguous -> GEMM stages with pure linear copies.
// ---------------------------------------------------------------------------

// Merged prep: blocks [0,2048) dequant qweight -> Wf; [2048,18432) cvt x -> Xf.
// Both use an LDS bounce: coalesced reads from row-major, 4KB-contiguous
// writes to the subtile-major layout.
__global__ __launch_bounds__(256) void prep_kernel(
    const int* __restrict__ q, const float* __restrict__ lut,
    __bf16* __restrict__ Wf,
    const float* __restrict__ x, __bf16* __restrict__ Xf) {
  __shared__ char sm[16384];
  const int b = blockIdx.x;
  const int tid = threadIdx.x;
  if (b < 2048) {
    // ---- dequant: block covers cols o0..o0+31 (one rg), w0..w0+7 (4 K-tiles)
    const int ob = b >> 4, wb = b & 15;
    const int o0 = ob * 32, w0 = wb * 8;
    const int o_l = tid >> 3, w_l = tid & 7;
    const int o = o0 + o_l, w = w0 + w_l;
    const int PLANE = N_DIM * (K_DIM / 32);
    const int base = o * (K_DIM / 32) + w;
    uint32_t q0 = (uint32_t)q[base];
    uint32_t q1 = (uint32_t)q[PLANE + base];
    uint32_t q2 = (uint32_t)q[2 * PLANE + base];
    uint32_t q3 = (uint32_t)q[3 * PLANE + base];
    const float* lrow = lut + o * 16;
    const int ti = w_l >> 1;
#pragma unroll
    for (int g = 0; g < 4; ++g) {
      const int ks = (w_l & 1) * 2 + (g >> 1);
      const int l  = o_l + ((g & 1) << 5);
      bf16x8 v;
#pragma unroll
      for (int j = 0; j < 8; ++j) {
        const int i = g * 8 + j;
        uint32_t idx = ((q0 >> i) & 1u) | (((q1 >> i) & 1u) << 1) |
                       (((q2 >> i) & 1u) << 2) | (((q3 >> i) & 1u) << 3);
        v[j] = (__bf16)lrow[idx];
      }
      *(bf16x8*)(sm + ti * 4096 + ks * 1024 + l * 16) = v;
    }
    __syncthreads();
    const int nt = o0 >> 8, h = (o0 >> 7) & 1, rg = (o0 >> 5) & 3;
    const int t0 = w0 >> 1;
    const size_t outb = ((size_t)(nt * 64 + t0)) * 32768 + h * 16384 + rg * 4096;
    char* wp = (char*)Wf + outb + tid * 16;
#pragma unroll
    for (int c = 0; c < 4; ++c)
      *(bf16x8*)(wp + (size_t)c * 32768) = *(bf16x8*)(sm + c * 4096 + tid * 16);
  } else {
    // ---- cvt: block covers rows row0..row0+31 (one rg), K-tile t (64 k)
    const int bb = b - 2048;
    const int rb = bb >> 6, t = bb & 63;
    const int row0 = rb * 32;
    const int r_l = tid >> 3, k8 = tid & 7;
    const float* src = x + (size_t)(row0 + r_l) * K_DIM + t * 64 + k8 * 8;
    f32x4 u = *(const f32x4*)src;
    f32x4 w4 = *(const f32x4*)(src + 4);
    bf16x8 v;
    v[0] = (__bf16)u[0];  v[1] = (__bf16)u[1];  v[2] = (__bf16)u[2];  v[3] = (__bf16)u[3];
    v[4] = (__bf16)w4[0]; v[5] = (__bf16)w4[1]; v[6] = (__bf16)w4[2]; v[7] = (__bf16)w4[3];
    const int ks = k8 >> 1, l = r_l + ((k8 & 1) << 5);
    *(bf16x8*)(sm + ks * 1024 + l * 16) = v;
    __syncthreads();
    const int mt = row0 >> 8, h = (row0 >> 7) & 1, rg = (row0 >> 5) & 3;
    const size_t outb = ((size_t)(mt * 64 + t)) * 32768 + h * 16384 + rg * 4096;
    *(bf16x8*)((char*)Xf + outb + tid * 16) = *(bf16x8*)(sm + tid * 16);
  }
}

// ---------------------------------------------------------------------------
// 256x256 bf16 GEMM, R12: R8 schedule FROZEN + subtile-major global layout.
// Staging = pure linear gld_lds (src/dst = base + tid*16). All ds_reads are
// base + lane*16 (ideal). MFMA = 32x32x16 (2495 TF ubench vs 2075 for 16x16).
// Per wave: out 128x64 = 2qm x (2mf x 32r) x (4wc..) ; LDA=8, LDB=4 b128 per
// call -> identical read/stage balance and vmcnt ledger as R8.
// ---------------------------------------------------------------------------
__global__ __launch_bounds__(512, 2) void anyprec_gemm_kernel(
    const __bf16* __restrict__ A,   // subtile-major Xf
    const __bf16* __restrict__ B,   // subtile-major Wf
    const float* __restrict__ bias,
    float* __restrict__ C) {
  __shared__ __bf16 lds[2][2][2][8192];   // [buf][mat][half][16KB]

  // XCD-aware bijective swizzle (512 wgs, 512%8==0)
  int bid = blockIdx.x;
  int swz = (bid & 7) * 64 + (bid >> 3);
  int mb = swz >> 4;    // 32 m-tiles
  int nb = swz & 15;    // 16 n-tiles

  const int tid  = threadIdx.x;
  const int lane = tid & 63;
  const int wid  = tid >> 6;
  const int wr   = wid >> 2;   // 0..1
  const int wc   = wid & 3;    // 0..3
  const int tid16  = tid * 16;
  const int lane16 = lane * 16;

  const char* gA = (const char*)A + (size_t)mb * 2097152;  // 64 tiles * 32KB
  const char* gB = (const char*)B + (size_t)nb * 2097152;

  f32x16 acc[2][2][2];
#pragma unroll
  for (int qm = 0; qm < 2; ++qm)
#pragma unroll
    for (int qn = 0; qn < 2; ++qn)
#pragma unroll
      for (int mf = 0; mf < 2; ++mf) acc[qm][qn][mf] = (f32x16)0.0f;

  bf16x8 a0[2][4], a1[2][4], b0[4], b1[4];

#define STAGE(mat, h, buf, t) {                                            \
    char* lb_ = (char*)&lds[buf][mat][h][0] + tid16;                       \
    const char* gb_ = (mat ? gB : gA) + (size_t)(t) * 32768               \
                      + (h) * 16384 + tid16;                               \
    GLD_LDS16(gb_,        lb_);                                            \
    GLD_LDS16(gb_ + 8192, lb_ + 8192); }

#define LDA(dst, qm, buf) {                                                \
    const char* p_ = (const char*)&lds[buf][0][qm][0] + wr * 8192          \
                     + lane16;                                             \
    _Pragma("unroll")                                                      \
    for (int mf = 0; mf < 2; ++mf)                                         \
      _Pragma("unroll")                                                    \
      for (int ks = 0; ks < 4; ++ks)                                       \
        dst[mf][ks] = *(const bf16x8*)(p_ + mf * 4096 + ks * 1024); }

#define LDB(dst, qn, buf) {                                                \
    const char* p_ = (const char*)&lds[buf][1][qn][0] + wc * 4096          \
                     + lane16;                                             \
    _Pragma("unroll")                                                      \
    for (int ks = 0; ks < 4; ++ks)                                         \
      dst[ks] = *(const bf16x8*)(p_ + ks * 1024); }

#define MMA(qm, qn, aa, bb) {                                              \
    _Pragma("unroll")                                                      \
    for (int ks = 0; ks < 4; ++ks)                                         \
      _Pragma("unroll")                                                    \
      for (int mf = 0; mf < 2; ++mf)                                       \
        acc[qm][qn][mf] = __builtin_amdgcn_mfma_f32_32x32x16_bf16(         \
            aa[mf][ks], bb[ks], acc[qm][qn][mf], 0, 0, 0); }

#define PRIO1 __builtin_amdgcn_s_setprio(1);
#define PRIO0 __builtin_amdgcn_s_setprio(0);
#define BAR   __builtin_amdgcn_s_barrier();
#define VMC(n) asm volatile("s_waitcnt vmcnt(" #n ")" ::: "memory");

  // ---- prologue: stage tile0 + A0,B1,A1 of tile1; collective-cert tile0
  STAGE(0, 0, 0, 0);  // A0(0)
  STAGE(1, 0, 0, 0);  // B0(0)
  STAGE(1, 1, 0, 0);  // B1(0)
  STAGE(0, 1, 0, 0);  // A1(0)
  STAGE(0, 0, 1, 1);  // A0(1)
  STAGE(1, 1, 1, 1);  // B1(1)
  STAGE(0, 1, 1, 1);  // A1(1)
  VMC(6); BAR;        // tile0 certified for ALL waves
  LDA(a0, 0, 0); LDB(b0, 0, 0);   // consumed in p1

  // ---- main loop: tiles E=2i (buf0), O=2i+1 (buf1), i = 0..30
  for (int i = 0; i < 31; ++i) {
    const int t1 = 2 * i + 1, t2 = 2 * i + 2, t3 = 2 * i + 3;
    // p1: MMA(0,0)E ; load B1(E) ; stage B0(O)
    STAGE(1, 0, 1, t1);
    PRIO1; LDB(b1, 1, 0); MMA(0, 0, a0, b0); PRIO0; BAR;
    // p2: MMA(0,1)E ; load A1(E) ; stage A0(E+2)
    STAGE(0, 0, 0, t2);
    PRIO1; LDA(a1, 1, 0); MMA(0, 1, a0, b1); PRIO0; BAR;
    // p3: MMA(1,1)E ; stage B1(E+2) ; COLLECTIVE cert of tile O at end
    STAGE(1, 1, 0, t2);
    PRIO1; MMA(1, 1, a1, b1); PRIO0; VMC(4); BAR;
    // p4: MMA(1,0)E ; load A0(O), B0(O) (certified) ; stage A1(E+2)
    STAGE(0, 1, 0, t2);
    PRIO1; LDA(a0, 0, 1); MMA(1, 0, a1, b0); LDB(b0, 0, 1); PRIO0; BAR;
    // p5: MMA(0,0)O ; load B1(O) ; stage B0(E+2)
    STAGE(1, 0, 0, t2);
    PRIO1; LDB(b1, 1, 1); MMA(0, 0, a0, b0); PRIO0; BAR;
    // p6: MMA(0,1)O ; load A1(O) ; stage A0(O+2)
    STAGE(0, 0, 1, t3);
    PRIO1; LDA(a1, 1, 1); MMA(0, 1, a0, b1); PRIO0; BAR;
    // p7: MMA(1,1)O ; stage B1(O+2) ; COLLECTIVE cert of tile E+2 at end
    STAGE(1, 1, 1, t3);
    PRIO1; MMA(1, 1, a1, b1); PRIO0; VMC(4); BAR;
    // p8: MMA(1,0)O ; load A0(E+2), B0(E+2) (certified) ; stage A1(O+2)
    STAGE(0, 1, 1, t3);
    PRIO1; LDA(a0, 0, 0); MMA(1, 0, a1, b0); LDB(b0, 0, 0); PRIO0; BAR;
  }

  // ---- tail: tiles 62 (buf0), 63 (buf1); regs hold a0,b0 of 62;
  //      outstanding stages: A0(63),B1(63),A1(63)
  STAGE(1, 0, 1, 63);                         // B0(63)
  PRIO1; LDB(b1, 1, 0); MMA(0, 0, a0, b0); PRIO0; BAR;
  PRIO1; LDA(a1, 1, 0); MMA(0, 1, a0, b1); PRIO0; BAR;
  PRIO1; MMA(1, 1, a1, b1); PRIO0; VMC(0); BAR;   // tile 63 collective-certified
  PRIO1; LDA(a0, 0, 1); MMA(1, 0, a1, b0); LDB(b0, 0, 1); PRIO0; BAR;
  PRIO1; LDB(b1, 1, 1); MMA(0, 0, a0, b0); PRIO0; BAR;
  PRIO1; LDA(a1, 1, 1); MMA(0, 1, a0, b1); PRIO0; BAR;
  MMA(1, 1, a1, b1);
  MMA(1, 0, a1, b0);

  // ---- epilogue: 32x32 C/D layout (R6-verified):
  // col = lane&31, row = (j&3) + 8*(j>>2) + 4*(lane>>5)
  const int cL = lane & 31;
  const int khalf = lane >> 5;
#pragma unroll
  for (int qn = 0; qn < 2; ++qn) {
    int col = nb * 256 + qn * 128 + wc * 32 + cL;
    float bv = bias[col];
#pragma unroll
    for (int qm = 0; qm < 2; ++qm)
#pragma unroll
      for (int mf = 0; mf < 2; ++mf) {
        int row0 = mb * 256 + qm * 128 + wr * 64 + mf * 32 + khalf * 4;
#pragma unroll
        for (int j = 0; j < 16; ++j) {
          int row = row0 + (j & 3) + 8 * (j >> 2);
          C[(size_t)row * N_DIM + col] = acc[qm][qn][mf][j] + bv;
        }
      }
  }
#undef STAGE
#undef LDA
#undef LDB
#undef MMA
#undef PRIO1
#undef PRIO0
#undef BAR
#undef VMC
}

extern "C" void kernel_launch(void* const* d_in, const int* in_sizes, int n_in,
                              void* d_out, int out_size, void* d_ws, size_t ws_size,
                              hipStream_t stream) {
  const float* x    = (const float*)d_in[0];
  const int*   qw   = (const int*)d_in[1];
  const float* lut  = (const float*)d_in[2];
  const float* bias = (const float*)d_in[3];

  __bf16* Wf = (__bf16*)d_ws;                                       // 32 MB
  __bf16* Xf = (__bf16*)((char*)d_ws + (size_t)N_DIM * K_DIM * 2);  // 64 MB

  {
    // 2048 dequant blocks + 16384 cvt blocks, one launch
    prep_kernel<<<18432, 256, 0, stream>>>(qw, lut, Wf, x, Xf);
  }
  {
    dim3 grid((M_DIM / 256) * (N_DIM / 256));  // 32*16 = 512
    anyprec_gemm_kernel<<<grid, 512, 0, stream>>>(Xf, Wf, bias, (float*)d_out);
  }
}

// Round 13
// 259.331 us; speedup vs baseline: 1.2015x; 1.0555x over previous
//
#include <hip/hip_runtime.h>
#include <hip/hip_bf16.h>
#include <stdint.h>

#define M_DIM 8192   // 4*2048
#define N_DIM 4096   // OUT_FEATURES
#define K_DIM 4096   // IN_FEATURES

typedef __attribute__((ext_vector_type(8))) __bf16 bf16x8;
typedef __attribute__((ext_vector_type(4))) float  f32x4;

#define GLD_LDS16(gaddr, laddr)                                            \
  __builtin_amdgcn_global_load_lds(                                        \
      (const __attribute__((address_space(1))) uint32_t*)(gaddr),          \
      (__attribute__((address_space(3))) uint32_t*)(laddr), 16, 0, 0)

// ---------------------------------------------------------------------------
// Subtile-major layout for 16x16x32 fragments (both Xf and Wf):
//  t = k>>6 (K-tile); rp = row>>8 (row panel); h = (row>>7)&1; f = (row>>4)&7;
//  ks = (k>>5)&1; lane slot l = (row&15) | (((k>>3)&3)<<4)
//  byte = (rp*64+t)*32768 + h*16384 + (f*2+ks)*1024 + l*16
// Half-tile (16 KB) contiguous -> GEMM stages with pure linear copies;
// GEMM fragment read = subtile_base + lane*16 (ideal).
// ---------------------------------------------------------------------------

// Merged prep: blocks [0,2048) dequant qweight -> Wf; [2048,18432) cvt x -> Xf.
__global__ __launch_bounds__(256) void prep_kernel(
    const int* __restrict__ q, const float* __restrict__ lut,
    __bf16* __restrict__ Wf,
    const float* __restrict__ x, __bf16* __restrict__ Xf) {
  __shared__ char sm[16384];
  const int b = blockIdx.x;
  const int tid = threadIdx.x;
  if (b < 2048) {
    // dequant: block covers cols o0..o0+31, q-words w0..w0+7 (4 K-tiles)
    const int ob = b >> 4, wb = b & 15;
    const int o0 = ob * 32, w0 = wb * 8;
    const int o_l = tid >> 3, w_l = tid & 7;
    const int o = o0 + o_l;
    const int PLANE = N_DIM * (K_DIM / 32);
    const int base = o * (K_DIM / 32) + (w0 + w_l);
    uint32_t q0 = (uint32_t)q[base];
    uint32_t q1 = (uint32_t)q[PLANE + base];
    uint32_t q2 = (uint32_t)q[2 * PLANE + base];
    uint32_t q3 = (uint32_t)q[3 * PLANE + base];
    const float* lrow = lut + o * 16;
    const int t_local = w_l >> 1;        // 0..3
    const int ks = w_l & 1;
    const int f_local = o_l >> 4;        // 0..1
#pragma unroll
    for (int g = 0; g < 4; ++g) {
      bf16x8 v;
#pragma unroll
      for (int j = 0; j < 8; ++j) {
        const int i = g * 8 + j;
        uint32_t idx = ((q0 >> i) & 1u) | (((q1 >> i) & 1u) << 1) |
                       (((q2 >> i) & 1u) << 2) | (((q3 >> i) & 1u) << 3);
        v[j] = (__bf16)lrow[idx];
      }
      const int l = (o_l & 15) | (g << 4);
      *(bf16x8*)(sm + t_local * 4096 + (f_local * 2 + ks) * 1024 + l * 16) = v;
    }
    __syncthreads();
    const int rp = ob >> 3, h = (ob >> 2) & 1, f0 = (ob * 2) & 7;
#pragma unroll
    for (int c = 0; c < 4; ++c) {
      const size_t outb = ((size_t)(rp * 64 + wb * 4 + c)) * 32768
                          + h * 16384 + f0 * 2048;
      *(bf16x8*)((char*)Wf + outb + tid * 16) = *(bf16x8*)(sm + c * 4096 + tid * 16);
    }
  } else {
    // cvt: block covers rows row0..row0+31, K-tile t
    const int bb = b - 2048;
    const int rb = bb >> 6, t = bb & 63;
    const int row0 = rb * 32;
    const int r_l = tid >> 3, k8 = tid & 7;
    const float* src = x + (size_t)(row0 + r_l) * K_DIM + t * 64 + k8 * 8;
    f32x4 u = *(const f32x4*)src;
    f32x4 w4 = *(const f32x4*)(src + 4);
    bf16x8 v;
    v[0] = (__bf16)u[0];  v[1] = (__bf16)u[1];  v[2] = (__bf16)u[2];  v[3] = (__bf16)u[3];
    v[4] = (__bf16)w4[0]; v[5] = (__bf16)w4[1]; v[6] = (__bf16)w4[2]; v[7] = (__bf16)w4[3];
    const int f_local = r_l >> 4, ks = k8 >> 2;
    const int l = (r_l & 15) | ((k8 & 3) << 4);
    *(bf16x8*)(sm + (f_local * 2 + ks) * 1024 + l * 16) = v;
    __syncthreads();
    const int rp = rb >> 3, h = (rb >> 2) & 1, f0 = (rb * 2) & 7;
    const size_t outb = ((size_t)(rp * 64 + t)) * 32768 + h * 16384 + f0 * 2048;
    *(bf16x8*)((char*)Xf + outb + tid * 16) = *(bf16x8*)(sm + tid * 16);
  }
}

// ---------------------------------------------------------------------------
// 256x256 bf16 GEMM, R13: 2 BIG PHASES per K-tile (2 barriers/tile), all reg
// loads one-phase-ahead, 16x16x32 MFMA, subtile-major linear LDS.
//  P1(t): [load a1(t) under MMA(0,0)+(0,1)] [stage A0,B0(t+2)] lgkm0 vmcnt(4) bar
//  P2(t): [load a0(t+1) | MMA(1,1) | load b1(t+1) | MMA(1,0) | load b0(t+1)]
//         [stage A1,B1(t+2)] lgkm0 bar
// Single vmcnt(4)/tile certifies tile t+1 fully at end-P1(t) (collective via
// barrier); lgkmcnt(0) before EVERY barrier closes cross-wave read/DMA WAR.
// ---------------------------------------------------------------------------
__global__ __launch_bounds__(512, 2) void anyprec_gemm_kernel(
    const __bf16* __restrict__ A,   // subtile-major Xf
    const __bf16* __restrict__ B,   // subtile-major Wf
    const float* __restrict__ bias,
    float* __restrict__ C) {
  __shared__ __bf16 lds[2][2][2][8192];   // [buf][mat][half][16KB] = 128 KiB

  // XCD-aware bijective swizzle (512 wgs, 512%8==0)
  int bid = blockIdx.x;
  int swz = (bid & 7) * 64 + (bid >> 3);
  int mb = swz >> 4;    // 32 m-tiles
  int nb = swz & 15;    // 16 n-tiles

  const int tid  = threadIdx.x;
  const int lane = tid & 63;
  const int wid  = tid >> 6;
  const int wr   = wid >> 2;   // 0..1
  const int wc   = wid & 3;    // 0..3
  const int tid16  = tid * 16;
  const int lane16 = lane * 16;

  const char* gA = (const char*)A + (size_t)mb * 2097152;  // 64 tiles * 32KB
  const char* gB = (const char*)B + (size_t)nb * 2097152;

  f32x4 acc[2][2][4][2];
#pragma unroll
  for (int qm = 0; qm < 2; ++qm)
#pragma unroll
    for (int qn = 0; qn < 2; ++qn)
#pragma unroll
      for (int mf = 0; mf < 4; ++mf)
#pragma unroll
        for (int nf = 0; nf < 2; ++nf) acc[qm][qn][mf][nf] = (f32x4)0.0f;

  bf16x8 a0[4][2], a1[4][2], b0[2][2], b1[2][2];

#define STAGE(mat, h, buf, t) {                                            \
    char* lb_ = (char*)&lds[buf][mat][h][0] + tid16;                       \
    const char* gb_ = (mat ? gB : gA) + (size_t)(t) * 32768                \
                      + (h) * 16384 + tid16;                               \
    GLD_LDS16(gb_,        lb_);                                            \
    GLD_LDS16(gb_ + 8192, lb_ + 8192); }

#define LDA(dst, qm, buf) {                                                \
    const char* p_ = (const char*)&lds[buf][0][qm][0] + wr * 8192          \
                     + lane16;                                             \
    _Pragma("unroll")                                                      \
    for (int mf = 0; mf < 4; ++mf) {                                       \
      dst[mf][0] = *(const bf16x8*)(p_ + mf * 2048);                       \
      dst[mf][1] = *(const bf16x8*)(p_ + mf * 2048 + 1024); } }

#define LDB(dst, qn, buf) {                                                \
    const char* p_ = (const char*)&lds[buf][1][qn][0] + wc * 4096          \
                     + lane16;                                             \
    _Pragma("unroll")                                                      \
    for (int nf = 0; nf < 2; ++nf) {                                       \
      dst[nf][0] = *(const bf16x8*)(p_ + nf * 2048);                       \
      dst[nf][1] = *(const bf16x8*)(p_ + nf * 2048 + 1024); } }

#define MMA(qm, qn, aa, bb) {                                              \
    _Pragma("unroll")                                                      \
    for (int mf = 0; mf < 4; ++mf)                                         \
      _Pragma("unroll")                                                    \
      for (int nf = 0; nf < 2; ++nf) {                                     \
        acc[qm][qn][mf][nf] = __builtin_amdgcn_mfma_f32_16x16x32_bf16(     \
            aa[mf][0], bb[nf][0], acc[qm][qn][mf][nf], 0, 0, 0);           \
        acc[qm][qn][mf][nf] = __builtin_amdgcn_mfma_f32_16x16x32_bf16(     \
            aa[mf][1], bb[nf][1], acc[qm][qn][mf][nf], 0, 0, 0); } }

#define PRIO1 __builtin_amdgcn_s_setprio(1);
#define PRIO0 __builtin_amdgcn_s_setprio(0);
#define BAR   __builtin_amdgcn_s_barrier();
#define LGKM0 asm volatile("s_waitcnt lgkmcnt(0)" ::: "memory");
#define VMC(n) asm volatile("s_waitcnt vmcnt(" #n ")" ::: "memory");

  // ---- prologue: stage tiles 0 (buf0) and 1 (buf1); certify tile0; preload
  STAGE(0, 0, 0, 0); STAGE(1, 0, 0, 0);   // A0,B0(0)
  STAGE(0, 1, 0, 0); STAGE(1, 1, 0, 0);   // A1,B1(0)
  STAGE(0, 0, 1, 1); STAGE(1, 0, 1, 1);   // A0,B0(1)
  STAGE(0, 1, 1, 1); STAGE(1, 1, 1, 1);   // A1,B1(1)
  VMC(8); BAR;                             // tile0 certified collectively
  LDA(a0, 0, 0); LDB(b0, 0, 0); LDB(b1, 1, 0);
  LGKM0; BAR;   // preload reads drained before P1(0)'s stages can overwrite

  // ---- main loop: i = 0..30, tiles t=2i (buf0) and t=2i+1 (buf1)
  for (int i = 0; i < 31; ++i) {
    const int t2 = 2 * i + 2, t3 = 2 * i + 3;
    // ======== tile E = 2i, buf 0 ========
    // P1(E)
    PRIO1; LDA(a1, 1, 0);
    MMA(0, 0, a0, b0); MMA(0, 1, a0, b1); PRIO0;
    STAGE(0, 0, 0, t2); STAGE(1, 0, 0, t2);     // A0,B0(E+2)
    LGKM0; VMC(4); BAR;                          // tile O certified
    // P2(E)
    PRIO1; LDA(a0, 0, 1);
    MMA(1, 1, a1, b1); LDB(b1, 1, 1);
    MMA(1, 0, a1, b0); LDB(b0, 0, 1); PRIO0;
    STAGE(0, 1, 0, t2); STAGE(1, 1, 0, t2);     // A1,B1(E+2)
    LGKM0; BAR;
    // ======== tile O = 2i+1, buf 1 ========
    // P1(O)
    PRIO1; LDA(a1, 1, 1);
    MMA(0, 0, a0, b0); MMA(0, 1, a0, b1); PRIO0;
    STAGE(0, 0, 1, t3); STAGE(1, 0, 1, t3);     // A0,B0(O+2)
    LGKM0; VMC(4); BAR;                          // tile E+2 certified
    // P2(O)
    PRIO1; LDA(a0, 0, 0);
    MMA(1, 1, a1, b1); LDB(b1, 1, 0);
    MMA(1, 0, a1, b0); LDB(b0, 0, 0); PRIO0;
    STAGE(0, 1, 1, t3); STAGE(1, 1, 1, t3);     // A1,B1(O+2)
    LGKM0; BAR;
  }

  // ---- tail: t=62 (buf0), t=63 (buf1); no more stages
  // P1(62): certify tile 63 fully
  PRIO1; LDA(a1, 1, 0);
  MMA(0, 0, a0, b0); MMA(0, 1, a0, b1); PRIO0;
  LGKM0; VMC(0); BAR;
  // P2(62)
  PRIO1; LDA(a0, 0, 1);
  MMA(1, 1, a1, b1); LDB(b1, 1, 1);
  MMA(1, 0, a1, b0); LDB(b0, 0, 1); PRIO0;
  LGKM0; BAR;
  // P1(63) + P2(63)
  PRIO1; LDA(a1, 1, 1);
  MMA(0, 0, a0, b0); MMA(0, 1, a0, b1);
  MMA(1, 1, a1, b1); MMA(1, 0, a1, b0); PRIO0;

  // ---- epilogue: C/D layout col=lane&15, row=(lane>>4)*4+j
  const int cL = lane & 15;
  const int rL = (lane >> 4) * 4;
#pragma unroll
  for (int qn = 0; qn < 2; ++qn)
#pragma unroll
    for (int nf = 0; nf < 2; ++nf) {
      int col = nb * 256 + qn * 128 + wc * 32 + nf * 16 + cL;
      float bv = bias[col];
#pragma unroll
      for (int qm = 0; qm < 2; ++qm)
#pragma unroll
        for (int mf = 0; mf < 4; ++mf) {
          int row0 = mb * 256 + qm * 128 + wr * 64 + mf * 16 + rL;
#pragma unroll
          for (int j = 0; j < 4; ++j)
            C[(size_t)(row0 + j) * N_DIM + col] = acc[qm][qn][mf][nf][j] + bv;
        }
    }
#undef STAGE
#undef LDA
#undef LDB
#undef MMA
#undef PRIO1
#undef PRIO0
#undef BAR
#undef LGKM0
#undef VMC
}

extern "C" void kernel_launch(void* const* d_in, const int* in_sizes, int n_in,
                              void* d_out, int out_size, void* d_ws, size_t ws_size,
                              hipStream_t stream) {
  const float* x    = (const float*)d_in[0];
  const int*   qw   = (const int*)d_in[1];
  const float* lut  = (const float*)d_in[2];
  const float* bias = (const float*)d_in[3];

  __bf16* Wf = (__bf16*)d_ws;                                       // 32 MB
  __bf16* Xf = (__bf16*)((char*)d_ws + (size_t)N_DIM * K_DIM * 2);  // 64 MB

  {
    prep_kernel<<<18432, 256, 0, stream>>>(qw, lut, Wf, x, Xf);
  }
  {
    dim3 grid((M_DIM / 256) * (N_DIM / 256));  // 32*16 = 512
    anyprec_gemm_kernel<<<grid, 512, 0, stream>>>(Xf, Wf, bias, (float*)d_out);
  }
}